// Round 1
// baseline (444.965 us; speedup 1.0000x reference)
//
#include <hip/hip_runtime.h>

// LIF recurrence: X [B,T,N] f32 -> spikes [B,T,N] f32
// B=32, T=64, N=32768. Independent per (b,n); sequential over t.
// Memory-streaming bound: 256 MiB read + 256 MiB write.

constexpr int B = 32;
constexpr int T = 64;
constexpr int N = 32768;
constexpr int N4 = N / 4;          // float4 granularity
constexpr int NTHREADS = B * N4;   // 262144 threads

__global__ __launch_bounds__(256) void lif_kernel(const float4* __restrict__ X,
                                                  float4* __restrict__ out) {
    // Match numpy's separately-rounded mul/add (no FMA contraction): a fused
    // (1+a*c)*x + m/tau changes rounding and can flip threshold decisions.
#pragma clang fp contract(off)
    const int i = blockIdx.x * blockDim.x + threadIdx.x;  // [0, B*N4)
    const int b = i >> 13;            // i / N4  (N4 = 8192)
    const int n4 = i & (N4 - 1);      // i % N4
    const long long base = (long long)b * T * N4 + n4;

    float mem0 = 0.f, mem1 = 0.f, mem2 = 0.f, mem3 = 0.f;
    float ca0 = 0.f, ca1 = 0.f, ca2 = 0.f, ca3 = 0.f;

    for (int t = 0; t < T; ++t) {
        const long long off = base + (long long)t * N4;
        const float4 xv = X[off];
        float4 sv;

        // lane 0
        {
            float m = mem0 / 5.0f + (1.0f + 0.1f * ca0) * xv.x;
            float s = ((m - 0.5f) > 0.0f) ? 1.0f : 0.0f;
            mem0 = (1.0f - s) * m;
            ca0 = 0.5f * ca0 + (1.0f - s);
            sv.x = s;
        }
        // lane 1
        {
            float m = mem1 / 5.0f + (1.0f + 0.1f * ca1) * xv.y;
            float s = ((m - 0.5f) > 0.0f) ? 1.0f : 0.0f;
            mem1 = (1.0f - s) * m;
            ca1 = 0.5f * ca1 + (1.0f - s);
            sv.y = s;
        }
        // lane 2
        {
            float m = mem2 / 5.0f + (1.0f + 0.1f * ca2) * xv.z;
            float s = ((m - 0.5f) > 0.0f) ? 1.0f : 0.0f;
            mem2 = (1.0f - s) * m;
            ca2 = 0.5f * ca2 + (1.0f - s);
            sv.z = s;
        }
        // lane 3
        {
            float m = mem3 / 5.0f + (1.0f + 0.1f * ca3) * xv.w;
            float s = ((m - 0.5f) > 0.0f) ? 1.0f : 0.0f;
            mem3 = (1.0f - s) * m;
            ca3 = 0.5f * ca3 + (1.0f - s);
            sv.w = s;
        }

        out[off] = sv;
    }
}

extern "C" void kernel_launch(void* const* d_in, const int* in_sizes, int n_in,
                              void* d_out, int out_size, void* d_ws, size_t ws_size,
                              hipStream_t stream) {
    const float4* X = (const float4*)d_in[0];
    float4* out = (float4*)d_out;
    const int block = 256;
    const int grid = NTHREADS / block;  // 1024 blocks
    lif_kernel<<<grid, block, 0, stream>>>(X, out);
}

// Round 2
// 440.783 us; speedup vs baseline: 1.0095x; 1.0095x over previous
//
#include <hip/hip_runtime.h>

// LIF recurrence: X [B,T,N] f32 -> spikes [B,T,N] f32
// B=32, T=64, N=32768. Independent per (b,n); sequential over t.
// Memory-streaming bound; R1 showed latency-bound at 2.4 TB/s.
// R2: float2/thread (8192 waves = full 32 waves/CU) + depth-2 prefetch
// pipeline to keep 2 loads in flight per wave.

constexpr int B = 32;
constexpr int T = 64;
constexpr int N = 32768;
constexpr int N2 = N / 2;          // float2 granularity = 16384
constexpr int NTHREADS = B * N2;   // 524288 threads = 8192 waves

__global__ __launch_bounds__(256) void lif_kernel(const float2* __restrict__ X,
                                                  float2* __restrict__ out) {
    // Match numpy's separately-rounded mul/add (no FMA contraction): fusing
    // changes rounding and can flip threshold decisions.
#pragma clang fp contract(off)
    const int i = blockIdx.x * blockDim.x + threadIdx.x;  // [0, B*N2)
    const int b = i >> 14;            // i / N2  (N2 = 16384)
    const int n2 = i & (N2 - 1);      // i % N2
    const int base = b * (T * N2) + n2;   // max ~33.5M, fits int

    float mem0 = 0.f, mem1 = 0.f;
    float ca0 = 0.f, ca1 = 0.f;

    // depth-2 software pipeline: x0 = x(t), x1 = x(t+1), prefetch x(t+2)
    float2 x0 = X[base];
    float2 x1 = X[base + N2];

    for (int t = 0; t < T; ++t) {
        const float2 xv = x0;
        x0 = x1;
        // clamp keeps the load unconditional (branchless, stays in flight);
        // tail loads just re-read the last element (L1/L2 hit, harmless).
        const int tp2 = (t + 2 < T) ? (t + 2) : (T - 1);
        x1 = X[base + tp2 * N2];

        float2 sv;
        // lane 0
        {
            float m = mem0 / 5.0f + (1.0f + 0.1f * ca0) * xv.x;
            float s = ((m - 0.5f) > 0.0f) ? 1.0f : 0.0f;
            mem0 = (1.0f - s) * m;
            ca0 = 0.5f * ca0 + (1.0f - s);
            sv.x = s;
        }
        // lane 1
        {
            float m = mem1 / 5.0f + (1.0f + 0.1f * ca1) * xv.y;
            float s = ((m - 0.5f) > 0.0f) ? 1.0f : 0.0f;
            mem1 = (1.0f - s) * m;
            ca1 = 0.5f * ca1 + (1.0f - s);
            sv.y = s;
        }

        out[base + t * N2] = sv;
    }
}

extern "C" void kernel_launch(void* const* d_in, const int* in_sizes, int n_in,
                              void* d_out, int out_size, void* d_ws, size_t ws_size,
                              hipStream_t stream) {
    const float2* X = (const float2*)d_in[0];
    float2* out = (float2*)d_out;
    const int block = 256;
    const int grid = NTHREADS / block;  // 2048 blocks
    lif_kernel<<<grid, block, 0, stream>>>(X, out);
}